// Round 2
// baseline (5007.401 us; speedup 1.0000x reference)
//
#include <hip/hip_runtime.h>

#define N_NODES 65536
#define N_EDGES 262144

typedef unsigned short u16;
typedef unsigned char u8;
typedef float f32x4 __attribute__((ext_vector_type(4)));
typedef __bf16 v8bf __attribute__((ext_vector_type(8)));

__device__ __forceinline__ u16 f2bf(float f) {
  unsigned u = __builtin_bit_cast(unsigned, f);
  u = u + 0x7fffu + ((u >> 16) & 1u);
  return (u16)(u >> 16);
}
__device__ __forceinline__ float bf2f(u16 h) {
  unsigned u = ((unsigned)h) << 16;
  return __builtin_bit_cast(float, u);
}
// 8-bit e5m2 == top byte of fp16 with RNE rounding. Zero exotic intrinsics.
__device__ __forceinline__ u8 f2e5m2(float f) {
  _Float16 h = (_Float16)f;
  u16 hb = __builtin_bit_cast(u16, h);
  hb = (u16)(hb + 0x7F + ((hb >> 8) & 1));
  return (u8)(hb >> 8);
}
// decode dword = 4 e5m2 bytes -> 4 floats
__device__ __forceinline__ void dec4(unsigned d, float* o) {
  o[0] = (float)__builtin_bit_cast(_Float16, (u16)((d << 8) & 0xFF00u));
  o[1] = (float)__builtin_bit_cast(_Float16, (u16)(d & 0xFF00u));
  o[2] = (float)__builtin_bit_cast(_Float16, (u16)((d >> 8) & 0xFF00u));
  o[3] = (float)__builtin_bit_cast(_Float16, (u16)((d >> 16) & 0xFF00u));
}
// load 8 bf16 from 16B-aligned LDS -> 8 floats
__device__ __forceinline__ void ld8bf(const u16* p, float* o) {
  uint4 v = *(const uint4*)p;
  unsigned d;
  d = v.x; o[0] = __builtin_bit_cast(float, d << 16); o[1] = __builtin_bit_cast(float, d & 0xFFFF0000u);
  d = v.y; o[2] = __builtin_bit_cast(float, d << 16); o[3] = __builtin_bit_cast(float, d & 0xFFFF0000u);
  d = v.z; o[4] = __builtin_bit_cast(float, d << 16); o[5] = __builtin_bit_cast(float, d & 0xFFFF0000u);
  d = v.w; o[6] = __builtin_bit_cast(float, d << 16); o[7] = __builtin_bit_cast(float, d & 0xFFFF0000u);
}
__device__ __forceinline__ float gelu_f(float x) {
  return 0.5f * x * (1.0f + erff(x * 0.70710678118654752f));
}

// ---------------- LayerNorm -> bf16 (one wave per 256-wide row) ----------------
__global__ __launch_bounds__(256) void ln_kernel(const float* __restrict__ x,
                                                 const float* __restrict__ g,
                                                 const float* __restrict__ b,
                                                 u16* __restrict__ out) {
  int row = blockIdx.x * 4 + (threadIdx.x >> 6);
  int lane = threadIdx.x & 63;
  float4 v = ((const float4*)(x + (size_t)row * 256))[lane];
  float s = v.x + v.y + v.z + v.w;
  float s2 = v.x * v.x + v.y * v.y + v.z * v.z + v.w * v.w;
#pragma unroll
  for (int off = 1; off < 64; off <<= 1) {
    s += __shfl_xor(s, off, 64);
    s2 += __shfl_xor(s2, off, 64);
  }
  float mean = s * (1.0f / 256.0f);
  float var = s2 * (1.0f / 256.0f) - mean * mean;
  float rs = rsqrtf(var + 1e-5f);
  float4 gv = ((const float4*)g)[lane];
  float4 bv = ((const float4*)b)[lane];
  ushort4 o;
  o.x = f2bf((v.x - mean) * rs * gv.x + bv.x);
  o.y = f2bf((v.y - mean) * rs * gv.y + bv.y);
  o.z = f2bf((v.z - mean) * rs * gv.z + bv.z);
  o.w = f2bf((v.w - mean) * rs * gv.w + bv.w);
  *(ushort4*)(out + (size_t)row * 256 + lane * 4) = o;
}

// ---------------- generic bf16 GEMM: C[m,n] = sum_k A[m,k] * BT[n,k] ----------------
template <typename Epi>
__global__ __launch_bounds__(256) void gemm_bt(const u16* __restrict__ A,
                                               const u16* __restrict__ BT,
                                               int K, Epi epi) {
  __shared__ __align__(16) u16 sA[128 * 48];
  __shared__ __align__(16) u16 sB[128 * 48];
  const int tm = blockIdx.x * 128, tn = blockIdx.y * 128;
  const int t = threadIdx.x;
  const int wave = t >> 6, lane = t & 63;
  const int lrow = lane & 15, quad = lane >> 4;
  const int wrow = (wave & 1) * 64, wcol = (wave >> 1) * 64;
  const int r = t >> 2, c = (t & 3) << 3;
  f32x4 acc[4][4];
  const f32x4 z = {0.f, 0.f, 0.f, 0.f};
#pragma unroll
  for (int i = 0; i < 4; ++i)
#pragma unroll
    for (int j = 0; j < 4; ++j) acc[i][j] = z;
  for (int k0 = 0; k0 < K; k0 += 32) {
    *(uint4*)&sA[r * 48 + c] = *(const uint4*)&A[(size_t)(tm + r) * K + k0 + c];
    *(uint4*)&sA[(r + 64) * 48 + c] = *(const uint4*)&A[(size_t)(tm + r + 64) * K + k0 + c];
    *(uint4*)&sB[r * 48 + c] = *(const uint4*)&BT[(size_t)(tn + r) * K + k0 + c];
    *(uint4*)&sB[(r + 64) * 48 + c] = *(const uint4*)&BT[(size_t)(tn + r + 64) * K + k0 + c];
    __syncthreads();
    v8bf af[4], bfv[4];
#pragma unroll
    for (int i = 0; i < 4; ++i) af[i] = *(const v8bf*)&sA[(wrow + i * 16 + lrow) * 48 + quad * 8];
#pragma unroll
    for (int j = 0; j < 4; ++j) bfv[j] = *(const v8bf*)&sB[(wcol + j * 16 + lrow) * 48 + quad * 8];
#pragma unroll
    for (int i = 0; i < 4; ++i)
#pragma unroll
      for (int j = 0; j < 4; ++j)
        acc[i][j] = __builtin_amdgcn_mfma_f32_16x16x32_bf16(af[i], bfv[j], acc[i][j], 0, 0, 0);
    __syncthreads();
  }
#pragma unroll
  for (int i = 0; i < 4; ++i)
#pragma unroll
    for (int j = 0; j < 4; ++j)
#pragma unroll
      for (int rg = 0; rg < 4; ++rg)
        epi(tm + wrow + i * 16 + quad * 4 + rg, tn + wcol + j * 16 + lrow, acc[i][j][rg]);
}

struct EpiAB {
  u8* out;
  __device__ void operator()(int m, int n, float v) const {
    out[(size_t)m * 3072 + n] = f2e5m2(v);
  }
};
struct EpiX2 {
  float* x2;
  const float* x1;
  const float* rb;
  __device__ void operator()(int m, int n, float v) const {
    x2[(size_t)m * 256 + n] = v + rb[n] + x1[(size_t)m * 256 + n];
  }
};
struct EpiHf {
  u16* hf;
  const float* b1;
  __device__ void operator()(int m, int n, float v) const {
    hf[(size_t)m * 512 + n] = f2bf(gelu_f(v + b1[n]));
  }
};
struct EpiOut {
  float* out;
  const float* b2;
  const float* x2;
  __device__ void operator()(int m, int n, float v) const {
    out[(size_t)m * 256 + n] = v + b2[n] + x2[(size_t)m * 256 + n];
  }
};

// ---------------- weight repacks (fp32 -> bf16, B-transposed) ----------------
__global__ void prep_w1catT(u16* __restrict__ out, const float* __restrict__ qW1,
                            const float* __restrict__ kW1, const float* __restrict__ vW1) {
  int cIdx = blockIdx.x;
  int rIdx = threadIdx.x;
  int sec = cIdx >> 9;
  int h = cIdx & 511;
  int mlp = sec % 3;
  const float* W1 = (mlp == 0) ? qW1 : (mlp == 1) ? kW1 : vW1;
  int rowoff = (sec < 3) ? 0 : 256;
  out[(size_t)cIdx * 256 + rIdx] = f2bf(W1[(size_t)(rowoff + rIdx) * 512 + h]);
}
__global__ void prep_w2T(u16* __restrict__ out, const float* __restrict__ qW2,
                         const float* __restrict__ kW2, const float* __restrict__ vW2) {
  int row = blockIdx.x;
  int m = row >> 8, n = row & 255;
  const float* W2 = (m == 0) ? qW2 : (m == 1) ? kW2 : vW2;
  for (int k = threadIdx.x; k < 512; k += 256)
    out[(size_t)row * 512 + k] = f2bf(W2[(size_t)k * 256 + n]);
}
__global__ void transpose_cast(u16* __restrict__ out, const float* __restrict__ in, int K, int Nn) {
  int n = blockIdx.x;
  for (int k = threadIdx.x; k < K; k += blockDim.x)
    out[(size_t)n * K + k] = f2bf(in[(size_t)k * Nn + n]);
}

// ---------------- fused edge kernel (32 edges/block, 78KB LDS, 2 blocks/CU) ----------------
__global__ __launch_bounds__(256) void edge_kernel(
    const int* __restrict__ eidx, const float* __restrict__ eattr,
    const u8* __restrict__ AB, const u16* __restrict__ W2T,
    const float* __restrict__ qb1, const float* __restrict__ kb1, const float* __restrict__ vb1,
    const float* __restrict__ qb2, const float* __restrict__ kb2, const float* __restrict__ vb2,
    const float* __restrict__ qW1, const float* __restrict__ kW1, const float* __restrict__ vW1,
    const float* __restrict__ sW1, const float* __restrict__ sb1,
    const float* __restrict__ sW2, const float* __restrict__ sb2,
    float* __restrict__ nsum, float* __restrict__ deg) {
  __shared__ __align__(16) u16 s_H[32][264];       // one 256-wide K-chunk of H (bf16)
  __shared__ __align__(16) u16 s_QKV[3][32][264];  // QKV in bf16
  __shared__ __align__(16) float s_S[32][8][8];
  __shared__ int s_src[32], s_dst[32];
  __shared__ __align__(16) float s_ea[32][8];
  __shared__ float s_bias[32][8];
  const int t = threadIdx.x;
  const int e0 = blockIdx.x * 32;
  if (t < 32) {
    s_src[t] = eidx[e0 + t];
    s_dst[t] = eidx[N_EDGES + e0 + t];
  }
  if (t < 224) {
    int i = t / 7, c = t % 7;
    s_ea[i][c] = eattr[(size_t)(e0 + i) * 7 + c];
  }
  __syncthreads();
  {  // s-MLP bias (relu MLP on edge_attr[:,3:7]) -> [32][8]
    int i = t >> 3, j = t & 7;
    float a0 = s_ea[i][3], a1 = s_ea[i][4], a2 = s_ea[i][5], a3 = s_ea[i][6];
    float acc = sb2[j];
    for (int h = 0; h < 64; ++h) {
      float zz = fmaxf(a0 * sW1[h] + a1 * sW1[64 + h] + a2 * sW1[128 + h] + a3 * sW1[192 + h] + sb1[h], 0.f);
      acc += zz * sW2[h * 8 + j];
    }
    s_bias[i][j] = acc;
  }
  const int lane = t & 63, wave = t >> 6;
  const int lrow = lane & 15, quad = lane >> 4;
  const int wcol = wave * 64;
  const int ei = t >> 3, sub = t & 7;
  const float* b1s[3] = {qb1, kb1, vb1};
  const float* b2s[3] = {qb2, kb2, vb2};
  const float* W1s[3] = {qW1, kW1, vW1};
  for (int m = 0; m < 3; ++m) {
    f32x4 acc[2][4];
    const f32x4 z = {0.f, 0.f, 0.f, 0.f};
#pragma unroll
    for (int i2 = 0; i2 < 2; ++i2)
#pragma unroll
      for (int j = 0; j < 4; ++j) acc[i2][j] = z;
    const u8* rs = AB + (size_t)s_src[ei] * 3072 + m * 512;
    const u8* rd = AB + (size_t)s_dst[ei] * 3072 + 1536 + m * 512;
    const float* w1e = W1s[m] + 512 * 512;  // W1 rows 512..514 (edge-attr rows)
    const float* b1 = b1s[m];
    const float a0 = s_ea[ei][0], a1 = s_ea[ei][1], a2 = s_ea[ei][2];
    const u16* wbase = W2T + (size_t)(m * 256 + wcol) * 512;
    for (int cch = 0; cch < 2; ++cch) {
      // assemble H chunk: cols [cch*256, cch*256+256)
#pragma unroll
      for (int half = 0; half < 2; ++half) {
        int lc = sub * 16 + half * 128;
        int gc = cch * 256 + lc;
        uint4 av = *(const uint4*)(rs + gc);
        uint4 bv = *(const uint4*)(rd + gc);
        float fa[16], fb[16];
        dec4(av.x, fa); dec4(av.y, fa + 4); dec4(av.z, fa + 8); dec4(av.w, fa + 12);
        dec4(bv.x, fb); dec4(bv.y, fb + 4); dec4(bv.z, fb + 8); dec4(bv.w, fb + 12);
        alignas(16) u16 ov[16];
#pragma unroll
        for (int u = 0; u < 16; ++u) {
          int cc = gc + u;
          float hh = fa[u] + fb[u] + a0 * w1e[cc] + a1 * w1e[512 + cc] + a2 * w1e[1024 + cc] + b1[cc];
          ov[u] = f2bf(gelu_f(hh));
        }
        *(uint4*)&s_H[ei][lc] = *(const uint4*)&ov[0];
        *(uint4*)&s_H[ei][lc + 8] = *(const uint4*)&ov[8];
      }
      __syncthreads();
      for (int k0 = 0; k0 < 256; k0 += 32) {
        v8bf af0 = *(const v8bf*)&s_H[lrow][k0 + quad * 8];
        v8bf af1 = *(const v8bf*)&s_H[16 + lrow][k0 + quad * 8];
        int gk = cch * 256 + k0 + quad * 8;
#pragma unroll
        for (int j = 0; j < 4; ++j) {
          v8bf bv = *(const v8bf*)&wbase[(size_t)(j * 16 + lrow) * 512 + gk];
          acc[0][j] = __builtin_amdgcn_mfma_f32_16x16x32_bf16(af0, bv, acc[0][j], 0, 0, 0);
          acc[1][j] = __builtin_amdgcn_mfma_f32_16x16x32_bf16(af1, bv, acc[1][j], 0, 0, 0);
        }
      }
      __syncthreads();
    }
    const float* b2 = b2s[m];
#pragma unroll
    for (int i2 = 0; i2 < 2; ++i2)
#pragma unroll
      for (int j = 0; j < 4; ++j)
#pragma unroll
        for (int rg = 0; rg < 4; ++rg) {
          int row = i2 * 16 + quad * 4 + rg;
          int col = wcol + j * 16 + lrow;
          s_QKV[m][row][col] = f2bf(acc[i2][j][rg] + b2[col]);
        }
  }
  __syncthreads();
  // scores: S[i][h][g] = Q[i,h]·K[i,g]/sqrt(32) + bias[i,h]
  {
    int i = t >> 3, h = t & 7;
    float q[32];
    ld8bf(&s_QKV[0][i][h * 32], q);
    ld8bf(&s_QKV[0][i][h * 32 + 8], q + 8);
    ld8bf(&s_QKV[0][i][h * 32 + 16], q + 16);
    ld8bf(&s_QKV[0][i][h * 32 + 24], q + 24);
    float bias = s_bias[i][h];
#pragma unroll
    for (int g = 0; g < 8; ++g) {
      float kk[32];
      ld8bf(&s_QKV[1][i][g * 32], kk);
      ld8bf(&s_QKV[1][i][g * 32 + 8], kk + 8);
      ld8bf(&s_QKV[1][i][g * 32 + 16], kk + 16);
      ld8bf(&s_QKV[1][i][g * 32 + 24], kk + 24);
      float sd = 0.f;
#pragma unroll
      for (int u = 0; u < 32; ++u) sd += q[u] * kk[u];
      s_S[i][h][g] = sd * 0.17677669529663687f + bias;
    }
  }
  __syncthreads();
  // softmax over h (axis=1) for each (i, g)
  {
    int i = t >> 3, g = t & 7;
    float mx = -1e30f;
#pragma unroll
    for (int h = 0; h < 8; ++h) mx = fmaxf(mx, s_S[i][h][g]);
    float ev[8], ssum = 0.f;
#pragma unroll
    for (int h = 0; h < 8; ++h) {
      ev[h] = __expf(s_S[i][h][g] - mx);
      ssum += ev[h];
    }
    float inv = 1.0f / ssum;
#pragma unroll
    for (int h = 0; h < 8; ++h) s_S[i][h][g] = ev[h] * inv;
  }
  __syncthreads();
  // wv[i,h,:] = sum_g attn[i,h,g] * V[i,g,:]; scatter-add to nsum[dst]
  {
    int i = t >> 3, h = t & 7;
    float at[8];
#pragma unroll
    for (int g = 0; g < 8; ++g) at[g] = s_S[i][h][g];
    float accv[32];
#pragma unroll
    for (int u = 0; u < 32; ++u) accv[u] = 0.f;
#pragma unroll
    for (int g = 0; g < 8; ++g) {
      float vv[32];
      ld8bf(&s_QKV[2][i][g * 32], vv);
      ld8bf(&s_QKV[2][i][g * 32 + 8], vv + 8);
      ld8bf(&s_QKV[2][i][g * 32 + 16], vv + 16);
      ld8bf(&s_QKV[2][i][g * 32 + 24], vv + 24);
#pragma unroll
      for (int u = 0; u < 32; ++u) accv[u] += at[g] * vv[u];
    }
    float* dp = nsum + (size_t)s_dst[i] * 256 + h * 32;
#pragma unroll
    for (int u = 0; u < 32; ++u) unsafeAtomicAdd(dp + u, accv[u]);
    if (h == 0) unsafeAtomicAdd(deg + s_dst[i], 1.0f);
  }
}

// ---------------- x1 = x + nsum/max(deg,1); X1cat = bf16([x1 | x]) ----------------
__global__ __launch_bounds__(256) void x1_build(const float* __restrict__ x,
                                                const float* __restrict__ nsum,
                                                const float* __restrict__ deg,
                                                float* __restrict__ x1,
                                                u16* __restrict__ X1cat) {
  int idx = blockIdx.x * 256 + threadIdx.x;  // over N*64
  int n = idx >> 6, q = idx & 63;
  float4 xv = ((const float4*)x)[idx];
  float4 sv = ((const float4*)nsum)[idx];
  float inv = 1.0f / fmaxf(deg[n], 1.0f);
  float4 x1v = {xv.x + sv.x * inv, xv.y + sv.y * inv, xv.z + sv.z * inv, xv.w + sv.w * inv};
  ((float4*)x1)[idx] = x1v;
  ushort4 a, bq;
  a.x = f2bf(x1v.x); a.y = f2bf(x1v.y); a.z = f2bf(x1v.z); a.w = f2bf(x1v.w);
  bq.x = f2bf(xv.x); bq.y = f2bf(xv.y); bq.z = f2bf(xv.z); bq.w = f2bf(xv.w);
  *(ushort4*)(X1cat + (size_t)n * 512 + q * 4) = a;
  *(ushort4*)(X1cat + (size_t)n * 512 + 256 + q * 4) = bq;
}

extern "C" void kernel_launch(void* const* d_in, const int* in_sizes, int n_in,
                              void* d_out, int out_size, void* d_ws, size_t ws_size,
                              hipStream_t stream) {
  const float* x = (const float*)d_in[0];
  const int* eidx = (const int*)d_in[1];
  const float* eattr = (const float*)d_in[2];
  const float* qW1 = (const float*)d_in[3];
  const float* qb1 = (const float*)d_in[4];
  const float* qW2 = (const float*)d_in[5];
  const float* qb2 = (const float*)d_in[6];
  const float* kW1 = (const float*)d_in[7];
  const float* kb1 = (const float*)d_in[8];
  const float* kW2 = (const float*)d_in[9];
  const float* kb2 = (const float*)d_in[10];
  const float* vW1 = (const float*)d_in[11];
  const float* vb1 = (const float*)d_in[12];
  const float* vW2 = (const float*)d_in[13];
  const float* vb2 = (const float*)d_in[14];
  const float* sW1 = (const float*)d_in[15];
  const float* sb1 = (const float*)d_in[16];
  const float* sW2 = (const float*)d_in[17];
  const float* sb2 = (const float*)d_in[18];
  const float* fW1 = (const float*)d_in[19];
  const float* fb1 = (const float*)d_in[20];
  const float* fW2 = (const float*)d_in[21];
  const float* fb2 = (const float*)d_in[22];
  const float* lng = (const float*)d_in[23];
  const float* lnb = (const float*)d_in[24];
  const float* rW = (const float*)d_in[25];
  const float* rb = (const float*)d_in[26];

  const size_t N = N_NODES;
  char* ws = (char*)d_ws;
  size_t off = 0;
  auto alloc = [&](size_t bytes) {
    void* p = ws + off;
    off = (off + bytes + 255) & ~(size_t)255;
    return p;
  };
  u16* W1catT = (u16*)alloc((size_t)3072 * 256 * 2);
  u16* W2T = (u16*)alloc((size_t)768 * 512 * 2);
  u16* rWT = (u16*)alloc((size_t)256 * 512 * 2);
  u16* fW1T = (u16*)alloc((size_t)512 * 256 * 2);
  u16* fW2T = (u16*)alloc((size_t)256 * 512 * 2);
  u16* xn = (u16*)alloc(N * 256 * 2);
  float* deg = (float*)alloc(N * 4);
  u8* AB = (u8*)alloc(N * 3072);  // e5m2, 201 MB; node-stage tensors alias it below
  // nsum accumulator lives in d_out (memset to 0, consumed by x1_build, then overwritten)
  float* nsum = (float*)d_out;
  float* x1 = (float*)AB;                             // 64 MB
  u16* X1cat = (u16*)(AB + (size_t)67108864);         // 64 MB
  float* x2 = (float*)(AB + (size_t)134217728);       // 64 MB (ends exactly at 192M = AB size)
  u16* xn2 = (u16*)AB;                                // 32 MB (x1 dead by then)
  u16* Hf = (u16*)(AB + (size_t)33554432);            // 64 MB (X1cat dead by then)

  hipMemsetAsync(d_out, 0, N * 256 * 4, stream);
  hipMemsetAsync(deg, 0, N * 4, stream);
  prep_w1catT<<<3072, 256, 0, stream>>>(W1catT, qW1, kW1, vW1);
  prep_w2T<<<768, 256, 0, stream>>>(W2T, qW2, kW2, vW2);
  transpose_cast<<<256, 256, 0, stream>>>(rWT, rW, 512, 256);
  transpose_cast<<<512, 256, 0, stream>>>(fW1T, fW1, 256, 512);
  transpose_cast<<<256, 256, 0, stream>>>(fW2T, fW2, 512, 256);

  ln_kernel<<<N_NODES / 4, 256, 0, stream>>>(x, lng, lnb, xn);
  gemm_bt<<<dim3(N_NODES / 128, 3072 / 128), 256, 0, stream>>>(xn, W1catT, 256, EpiAB{AB});
  edge_kernel<<<N_EDGES / 32, 256, 0, stream>>>(eidx, eattr, AB, W2T, qb1, kb1, vb1, qb2, kb2,
                                                vb2, qW1, kW1, vW1, sW1, sb1, sW2, sb2, nsum, deg);
  x1_build<<<N_NODES * 64 / 256, 256, 0, stream>>>(x, nsum, deg, x1, X1cat);
  gemm_bt<<<dim3(N_NODES / 128, 2), 256, 0, stream>>>(X1cat, rWT, 512, EpiX2{x2, x1, rb});
  ln_kernel<<<N_NODES / 4, 256, 0, stream>>>(x2, lng, lnb, xn2);
  gemm_bt<<<dim3(N_NODES / 128, 4), 256, 0, stream>>>(xn2, fW1T, 256, EpiHf{Hf, fb1});
  gemm_bt<<<dim3(N_NODES / 128, 2), 256, 0, stream>>>(Hf, fW2T, 512, EpiOut{(float*)d_out, fb2, x2});
}

// Round 3
// 2326.811 us; speedup vs baseline: 2.1520x; 2.1520x over previous
//
#include <hip/hip_runtime.h>

#define N_NODES 65536
#define N_EDGES 262144

typedef unsigned short u16;
typedef unsigned char u8;
typedef float f32x4 __attribute__((ext_vector_type(4)));
typedef __bf16 v8bf __attribute__((ext_vector_type(8)));

__device__ __forceinline__ u16 f2bf(float f) {
  unsigned u = __builtin_bit_cast(unsigned, f);
  u = u + 0x7fffu + ((u >> 16) & 1u);
  return (u16)(u >> 16);
}
// 8-bit e5m2 == top byte of fp16 with RNE rounding.
__device__ __forceinline__ u8 f2e5m2(float f) {
  _Float16 h = (_Float16)f;
  u16 hb = __builtin_bit_cast(u16, h);
  hb = (u16)(hb + 0x7F + ((hb >> 8) & 1));
  return (u8)(hb >> 8);
}
// decode dword = 4 e5m2 bytes -> 4 floats
__device__ __forceinline__ void dec4(unsigned d, float* o) {
  o[0] = (float)__builtin_bit_cast(_Float16, (u16)((d << 8) & 0xFF00u));
  o[1] = (float)__builtin_bit_cast(_Float16, (u16)(d & 0xFF00u));
  o[2] = (float)__builtin_bit_cast(_Float16, (u16)((d >> 8) & 0xFF00u));
  o[3] = (float)__builtin_bit_cast(_Float16, (u16)((d >> 16) & 0xFF00u));
}
__device__ __forceinline__ void ld32f8(const u8* p, float* o) {
  uint4 v0 = *(const uint4*)p;
  uint4 v1 = *(const uint4*)(p + 16);
  dec4(v0.x, o); dec4(v0.y, o + 4); dec4(v0.z, o + 8); dec4(v0.w, o + 12);
  dec4(v1.x, o + 16); dec4(v1.y, o + 20); dec4(v1.z, o + 24); dec4(v1.w, o + 28);
}
// tanh-form gelu: x*E/(E+1), E=exp(1.5958*(x+0.044715x^3)); ~9 VALU ops, |err|<~1.5e-3
__device__ __forceinline__ float gelu_f(float x) {
  float y = 1.5957691216057308f * (x + 0.044715f * x * x * x);
  float e = __expf(y);
  return x - __fdividef(x, e + 1.0f);
}

// ---------------- LayerNorm -> bf16 (one wave per 256-wide row) ----------------
__global__ __launch_bounds__(256) void ln_kernel(const float* __restrict__ x,
                                                 const float* __restrict__ g,
                                                 const float* __restrict__ b,
                                                 u16* __restrict__ out) {
  int row = blockIdx.x * 4 + (threadIdx.x >> 6);
  int lane = threadIdx.x & 63;
  float4 v = ((const float4*)(x + (size_t)row * 256))[lane];
  float s = v.x + v.y + v.z + v.w;
  float s2 = v.x * v.x + v.y * v.y + v.z * v.z + v.w * v.w;
#pragma unroll
  for (int off = 1; off < 64; off <<= 1) {
    s += __shfl_xor(s, off, 64);
    s2 += __shfl_xor(s2, off, 64);
  }
  float mean = s * (1.0f / 256.0f);
  float var = s2 * (1.0f / 256.0f) - mean * mean;
  float rs = rsqrtf(var + 1e-5f);
  float4 gv = ((const float4*)g)[lane];
  float4 bv = ((const float4*)b)[lane];
  ushort4 o;
  o.x = f2bf((v.x - mean) * rs * gv.x + bv.x);
  o.y = f2bf((v.y - mean) * rs * gv.y + bv.y);
  o.z = f2bf((v.z - mean) * rs * gv.z + bv.z);
  o.w = f2bf((v.w - mean) * rs * gv.w + bv.w);
  *(ushort4*)(out + (size_t)row * 256 + lane * 4) = o;
}

// ---------------- generic bf16 GEMM: C[m,n] = sum_k A[m,k] * BT[n,k] ----------------
template <typename Epi>
__global__ __launch_bounds__(256) void gemm_bt(const u16* __restrict__ A,
                                               const u16* __restrict__ BT,
                                               int K, Epi epi) {
  __shared__ __align__(16) u16 sA[128 * 48];
  __shared__ __align__(16) u16 sB[128 * 48];
  const int tm = blockIdx.x * 128, tn = blockIdx.y * 128;
  const int t = threadIdx.x;
  const int wave = t >> 6, lane = t & 63;
  const int lrow = lane & 15, quad = lane >> 4;
  const int wrow = (wave & 1) * 64, wcol = (wave >> 1) * 64;
  const int r = t >> 2, c = (t & 3) << 3;
  f32x4 acc[4][4];
  const f32x4 z = {0.f, 0.f, 0.f, 0.f};
#pragma unroll
  for (int i = 0; i < 4; ++i)
#pragma unroll
    for (int j = 0; j < 4; ++j) acc[i][j] = z;
  for (int k0 = 0; k0 < K; k0 += 32) {
    *(uint4*)&sA[r * 48 + c] = *(const uint4*)&A[(size_t)(tm + r) * K + k0 + c];
    *(uint4*)&sA[(r + 64) * 48 + c] = *(const uint4*)&A[(size_t)(tm + r + 64) * K + k0 + c];
    *(uint4*)&sB[r * 48 + c] = *(const uint4*)&BT[(size_t)(tn + r) * K + k0 + c];
    *(uint4*)&sB[(r + 64) * 48 + c] = *(const uint4*)&BT[(size_t)(tn + r + 64) * K + k0 + c];
    __syncthreads();
    v8bf af[4], bfv[4];
#pragma unroll
    for (int i = 0; i < 4; ++i) af[i] = *(const v8bf*)&sA[(wrow + i * 16 + lrow) * 48 + quad * 8];
#pragma unroll
    for (int j = 0; j < 4; ++j) bfv[j] = *(const v8bf*)&sB[(wcol + j * 16 + lrow) * 48 + quad * 8];
#pragma unroll
    for (int i = 0; i < 4; ++i)
#pragma unroll
      for (int j = 0; j < 4; ++j)
        acc[i][j] = __builtin_amdgcn_mfma_f32_16x16x32_bf16(af[i], bfv[j], acc[i][j], 0, 0, 0);
    __syncthreads();
  }
#pragma unroll
  for (int i = 0; i < 4; ++i)
#pragma unroll
    for (int j = 0; j < 4; ++j)
#pragma unroll
      for (int rg = 0; rg < 4; ++rg)
        epi(tm + wrow + i * 16 + quad * 4 + rg, tn + wcol + j * 16 + lrow, acc[i][j][rg]);
}

struct EpiAB {
  u8* out;
  __device__ void operator()(int m, int n, float v) const {
    out[(size_t)m * 3072 + n] = f2e5m2(v);
  }
};
struct EpiX2 {
  float* x2;
  const float* x1;
  const float* rb;
  __device__ void operator()(int m, int n, float v) const {
    x2[(size_t)m * 256 + n] = v + rb[n] + x1[(size_t)m * 256 + n];
  }
};
struct EpiHf {
  u16* hf;
  const float* b1;
  __device__ void operator()(int m, int n, float v) const {
    hf[(size_t)m * 512 + n] = f2bf(gelu_f(v + b1[n]));
  }
};
struct EpiOut {
  float* out;
  const float* b2;
  const float* x2;
  __device__ void operator()(int m, int n, float v) const {
    out[(size_t)m * 256 + n] = v + b2[n] + x2[(size_t)m * 256 + n];
  }
};

// ---------------- weight repacks (fp32 -> bf16, B-transposed) ----------------
__global__ void prep_w1catT(u16* __restrict__ out, const float* __restrict__ qW1,
                            const float* __restrict__ kW1, const float* __restrict__ vW1) {
  int cIdx = blockIdx.x;
  int rIdx = threadIdx.x;
  int sec = cIdx >> 9;
  int h = cIdx & 511;
  int mlp = sec % 3;
  const float* W1 = (mlp == 0) ? qW1 : (mlp == 1) ? kW1 : vW1;
  int rowoff = (sec < 3) ? 0 : 256;
  out[(size_t)cIdx * 256 + rIdx] = f2bf(W1[(size_t)(rowoff + rIdx) * 512 + h]);
}
__global__ void prep_w2T(u16* __restrict__ out, const float* __restrict__ qW2,
                         const float* __restrict__ kW2, const float* __restrict__ vW2) {
  int row = blockIdx.x;
  int m = row >> 8, n = row & 255;
  const float* W2 = (m == 0) ? qW2 : (m == 1) ? kW2 : vW2;
  for (int k = threadIdx.x; k < 512; k += 256)
    out[(size_t)row * 512 + k] = f2bf(W2[(size_t)k * 256 + n]);
}
__global__ void transpose_cast(u16* __restrict__ out, const float* __restrict__ in, int K, int Nn) {
  int n = blockIdx.x;
  for (int k = threadIdx.x; k < K; k += blockDim.x)
    out[(size_t)n * K + k] = f2bf(in[(size_t)k * Nn + n]);
}

// ---------------- CSR build: histogram -> scan -> id scatter ----------------
__global__ __launch_bounds__(256) void hist_kernel(const int* __restrict__ dst,
                                                   unsigned* __restrict__ cnt) {
  int e = blockIdx.x * 256 + threadIdx.x;
  atomicAdd(&cnt[dst[e]], 1u);
}
__global__ __launch_bounds__(1024) void scan_kernel(const unsigned* __restrict__ cnt,
                                                    unsigned* __restrict__ off,
                                                    unsigned* __restrict__ woff) {
  __shared__ unsigned s_part[1024];
  int t = threadIdx.x;
  unsigned local[64];
  unsigned run = 0;
  const uint4* cp = (const uint4*)(cnt + t * 64);
#pragma unroll
  for (int j = 0; j < 16; ++j) {
    uint4 v = cp[j];
    local[j * 4 + 0] = v.x; local[j * 4 + 1] = v.y;
    local[j * 4 + 2] = v.z; local[j * 4 + 3] = v.w;
  }
#pragma unroll
  for (int j = 0; j < 64; ++j) { unsigned c = local[j]; local[j] = run; run += c; }
  s_part[t] = run;
  __syncthreads();
  for (int d = 1; d < 1024; d <<= 1) {
    unsigned v = (t >= d) ? s_part[t - d] : 0u;
    __syncthreads();
    s_part[t] += v;
    __syncthreads();
  }
  unsigned base = (t == 0) ? 0u : s_part[t - 1];
  for (int j = 0; j < 64; ++j) {
    unsigned o = base + local[j];
    off[t * 64 + j] = o;
    woff[t * 64 + j] = o;
  }
}
__global__ __launch_bounds__(256) void scatter_ids(const int* __restrict__ dst,
                                                   unsigned* __restrict__ woff,
                                                   unsigned* __restrict__ eid) {
  int e = blockIdx.x * 256 + threadIdx.x;
  unsigned pos = atomicAdd(&woff[dst[e]], 1u);
  eid[pos] = (unsigned)e;
}

// ---------------- s-MLP bias precompute: sbias[e][h] ----------------
__global__ __launch_bounds__(256) void sbias_kernel(const float* __restrict__ eattr,
                                                    const float* __restrict__ sW1,
                                                    const float* __restrict__ sb1,
                                                    const float* __restrict__ sW2,
                                                    const float* __restrict__ sb2,
                                                    float* __restrict__ sbias) {
  int idx = blockIdx.x * 256 + threadIdx.x;  // e*8 + h
  int e = idx >> 3, h = idx & 7;
  const float* ea = eattr + (size_t)e * 7;
  float a0 = ea[3], a1 = ea[4], a2 = ea[5], a3 = ea[6];
  float acc = sb2[h];
#pragma unroll 4
  for (int j = 0; j < 64; ++j) {
    float zz = fmaxf(a0 * sW1[j] + a1 * sW1[64 + j] + a2 * sW1[128 + j] + a3 * sW1[192 + j] + sb1[j], 0.f);
    acc += zz * sW2[j * 8 + h];
  }
  sbias[idx] = acc;
}

// ---------------- fused edge kernel (32 edges/block, ~45KB LDS, 3 blocks/CU) ----------------
__global__ __launch_bounds__(256) void edge_kernel(
    const int* __restrict__ eidx, const float* __restrict__ eattr,
    const u8* __restrict__ AB, const u16* __restrict__ W2T,
    const float* __restrict__ qb1, const float* __restrict__ kb1, const float* __restrict__ vb1,
    const float* __restrict__ qb2, const float* __restrict__ kb2, const float* __restrict__ vb2,
    const float* __restrict__ qW1, const float* __restrict__ kW1, const float* __restrict__ vW1,
    const float* __restrict__ sbias, u8* __restrict__ wv) {
  __shared__ __align__(16) union {
    u16 H[32][264];
    float S[32][8][8];
  } s_hs;
  __shared__ __align__(16) u8 s_QKV[3][32][272];
  __shared__ int s_src[32], s_dst[32];
  __shared__ __align__(16) float s_ea[32][4];
  __shared__ float s_bias[32][8];
  const int t = threadIdx.x;
  const int e0 = blockIdx.x * 32;
  if (t < 32) {
    s_src[t] = eidx[e0 + t];
    s_dst[t] = eidx[N_EDGES + e0 + t];
  }
  if (t < 128) {
    int i = t >> 2, c = t & 3;
    if (c < 3) s_ea[i][c] = eattr[(size_t)(e0 + i) * 7 + c];
  }
  {
    int i = t >> 3, h = t & 7;
    s_bias[i][h] = sbias[(size_t)(e0 + i) * 8 + h];
  }
  __syncthreads();
  const int lane = t & 63, wave = t >> 6;
  const int lrow = lane & 15, quad = lane >> 4;
  const int wcol = wave * 64;
  const int ei = t >> 3, sub = t & 7;
  const float* b1s[3] = {qb1, kb1, vb1};
  const float* b2s[3] = {qb2, kb2, vb2};
  const float* W1s[3] = {qW1, kW1, vW1};
  for (int m = 0; m < 3; ++m) {
    f32x4 acc[2][4];
    const f32x4 z = {0.f, 0.f, 0.f, 0.f};
#pragma unroll
    for (int i2 = 0; i2 < 2; ++i2)
#pragma unroll
      for (int j = 0; j < 4; ++j) acc[i2][j] = z;
    const u8* rs = AB + (size_t)s_src[ei] * 3072 + m * 512;
    const u8* rd = AB + (size_t)s_dst[ei] * 3072 + 1536 + m * 512;
    const float* w1e = W1s[m] + 512 * 512;  // W1 rows 512..514 (edge-attr rows)
    const float* b1 = b1s[m];
    const float a0 = s_ea[ei][0], a1 = s_ea[ei][1], a2 = s_ea[ei][2];
    const u16* wbase = W2T + (size_t)(m * 256 + wcol) * 512;
    for (int cch = 0; cch < 2; ++cch) {
#pragma unroll
      for (int half = 0; half < 2; ++half) {
        int lc = sub * 16 + half * 128;
        int gc = cch * 256 + lc;
        uint4 av = *(const uint4*)(rs + gc);
        uint4 bv = *(const uint4*)(rd + gc);
        float fa[16], fb[16];
        dec4(av.x, fa); dec4(av.y, fa + 4); dec4(av.z, fa + 8); dec4(av.w, fa + 12);
        dec4(bv.x, fb); dec4(bv.y, fb + 4); dec4(bv.z, fb + 8); dec4(bv.w, fb + 12);
        alignas(16) u16 ov[16];
#pragma unroll
        for (int u = 0; u < 16; ++u) {
          int cc = gc + u;
          float hh = fa[u] + fb[u] + a0 * w1e[cc] + a1 * w1e[512 + cc] + a2 * w1e[1024 + cc] + b1[cc];
          ov[u] = f2bf(gelu_f(hh));
        }
        *(uint4*)&s_hs.H[ei][lc] = *(const uint4*)&ov[0];
        *(uint4*)&s_hs.H[ei][lc + 8] = *(const uint4*)&ov[8];
      }
      __syncthreads();
      for (int k0 = 0; k0 < 256; k0 += 32) {
        v8bf af0 = *(const v8bf*)&s_hs.H[lrow][k0 + quad * 8];
        v8bf af1 = *(const v8bf*)&s_hs.H[16 + lrow][k0 + quad * 8];
        int gk = cch * 256 + k0 + quad * 8;
#pragma unroll
        for (int j = 0; j < 4; ++j) {
          v8bf bv = *(const v8bf*)&wbase[(size_t)(j * 16 + lrow) * 512 + gk];
          acc[0][j] = __builtin_amdgcn_mfma_f32_16x16x32_bf16(af0, bv, acc[0][j], 0, 0, 0);
          acc[1][j] = __builtin_amdgcn_mfma_f32_16x16x32_bf16(af1, bv, acc[1][j], 0, 0, 0);
        }
      }
      __syncthreads();
    }
    const float* b2 = b2s[m];
#pragma unroll
    for (int i2 = 0; i2 < 2; ++i2)
#pragma unroll
      for (int j = 0; j < 4; ++j)
#pragma unroll
        for (int rg = 0; rg < 4; ++rg) {
          int row = i2 * 16 + quad * 4 + rg;
          int col = wcol + j * 16 + lrow;
          s_QKV[m][row][col] = f2e5m2(acc[i2][j][rg] + b2[col]);
        }
  }
  __syncthreads();
  // scores: S[i][h][g] = Q[i,h]·K[i,g]/sqrt(32) + bias[i,h]
  {
    int i = t >> 3, h = t & 7;
    float q[32];
    ld32f8(&s_QKV[0][i][h * 32], q);
    float bias = s_bias[i][h];
#pragma unroll
    for (int g = 0; g < 8; ++g) {
      float kk[32];
      ld32f8(&s_QKV[1][i][g * 32], kk);
      float sd = 0.f;
#pragma unroll
      for (int u = 0; u < 32; ++u) sd += q[u] * kk[u];
      s_hs.S[i][h][g] = sd * 0.17677669529663687f + bias;
    }
  }
  __syncthreads();
  // softmax over h (axis=1) for each (i, g)
  {
    int i = t >> 3, g = t & 7;
    float mx = -1e30f;
#pragma unroll
    for (int h = 0; h < 8; ++h) mx = fmaxf(mx, s_hs.S[i][h][g]);
    float ev[8], ssum = 0.f;
#pragma unroll
    for (int h = 0; h < 8; ++h) {
      ev[h] = __expf(s_hs.S[i][h][g] - mx);
      ssum += ev[h];
    }
    float inv = 1.0f / ssum;
#pragma unroll
    for (int h = 0; h < 8; ++h) s_hs.S[i][h][g] = ev[h] * inv;
  }
  __syncthreads();
  // wv[e][h*32..] = sum_g attn[h][g] * V[g][:], coalesced fp8 store
  {
    int i = t >> 3, h = t & 7;
    float at[8];
#pragma unroll
    for (int g = 0; g < 8; ++g) at[g] = s_hs.S[i][h][g];
    float accv[32];
#pragma unroll
    for (int u = 0; u < 32; ++u) accv[u] = 0.f;
#pragma unroll
    for (int g = 0; g < 8; ++g) {
      float vv[32];
      ld32f8(&s_QKV[2][i][g * 32], vv);
#pragma unroll
      for (int u = 0; u < 32; ++u) accv[u] += at[g] * vv[u];
    }
    alignas(16) u8 ob[32];
#pragma unroll
    for (int u = 0; u < 32; ++u) ob[u] = f2e5m2(accv[u]);
    u8* dp = wv + (size_t)(e0 + i) * 256 + h * 32;
    *(uint4*)dp = *(const uint4*)ob;
    *(uint4*)(dp + 16) = *(const uint4*)(ob + 16);
  }
}

// ---------------- node gather-mean + x1/X1cat build ----------------
__global__ __launch_bounds__(256) void node_gather(const unsigned* __restrict__ off,
                                                   const unsigned* __restrict__ cnt,
                                                   const unsigned* __restrict__ eid,
                                                   const u8* __restrict__ wv,
                                                   const float* __restrict__ x,
                                                   float* __restrict__ x1,
                                                   u16* __restrict__ X1cat) {
  int n = blockIdx.x * 4 + (threadIdx.x >> 6);
  int lane = threadIdx.x & 63;
  unsigned st = off[n], c = cnt[n];
  float a0 = 0.f, a1 = 0.f, a2 = 0.f, a3 = 0.f;
  for (unsigned j = 0; j < c; ++j) {
    unsigned e = eid[st + j];
    unsigned d = *(const unsigned*)(wv + (size_t)e * 256 + lane * 4);
    float f[4];
    dec4(d, f);
    a0 += f[0]; a1 += f[1]; a2 += f[2]; a3 += f[3];
  }
  float inv = 1.0f / fmaxf((float)c, 1.0f);
  float4 xv = *(const float4*)(x + (size_t)n * 256 + lane * 4);
  float4 x1v = {xv.x + a0 * inv, xv.y + a1 * inv, xv.z + a2 * inv, xv.w + a3 * inv};
  *(float4*)(x1 + (size_t)n * 256 + lane * 4) = x1v;
  ushort4 a, bq;
  a.x = f2bf(x1v.x); a.y = f2bf(x1v.y); a.z = f2bf(x1v.z); a.w = f2bf(x1v.w);
  bq.x = f2bf(xv.x); bq.y = f2bf(xv.y); bq.z = f2bf(xv.z); bq.w = f2bf(xv.w);
  *(ushort4*)(X1cat + (size_t)n * 512 + lane * 4) = a;
  *(ushort4*)(X1cat + (size_t)n * 512 + 256 + lane * 4) = bq;
}

extern "C" void kernel_launch(void* const* d_in, const int* in_sizes, int n_in,
                              void* d_out, int out_size, void* d_ws, size_t ws_size,
                              hipStream_t stream) {
  const float* x = (const float*)d_in[0];
  const int* eidx = (const int*)d_in[1];
  const float* eattr = (const float*)d_in[2];
  const float* qW1 = (const float*)d_in[3];
  const float* qb1 = (const float*)d_in[4];
  const float* qW2 = (const float*)d_in[5];
  const float* qb2 = (const float*)d_in[6];
  const float* kW1 = (const float*)d_in[7];
  const float* kb1 = (const float*)d_in[8];
  const float* kW2 = (const float*)d_in[9];
  const float* kb2 = (const float*)d_in[10];
  const float* vW1 = (const float*)d_in[11];
  const float* vb1 = (const float*)d_in[12];
  const float* vW2 = (const float*)d_in[13];
  const float* vb2 = (const float*)d_in[14];
  const float* sW1 = (const float*)d_in[15];
  const float* sb1 = (const float*)d_in[16];
  const float* sW2 = (const float*)d_in[17];
  const float* sb2 = (const float*)d_in[18];
  const float* fW1 = (const float*)d_in[19];
  const float* fb1 = (const float*)d_in[20];
  const float* fW2 = (const float*)d_in[21];
  const float* fb2 = (const float*)d_in[22];
  const float* lng = (const float*)d_in[23];
  const float* lnb = (const float*)d_in[24];
  const float* rW = (const float*)d_in[25];
  const float* rb = (const float*)d_in[26];

  const size_t N = N_NODES;
  char* ws = (char*)d_ws;
  size_t off_b = 0;
  auto alloc = [&](size_t bytes) {
    void* p = ws + off_b;
    off_b = (off_b + bytes + 255) & ~(size_t)255;
    return p;
  };
  u16* W1catT = (u16*)alloc((size_t)3072 * 256 * 2);
  u16* W2T = (u16*)alloc((size_t)768 * 512 * 2);
  u16* rWT = (u16*)alloc((size_t)256 * 512 * 2);
  u16* fW1T = (u16*)alloc((size_t)512 * 256 * 2);
  u16* fW2T = (u16*)alloc((size_t)256 * 512 * 2);
  u16* xn = (u16*)alloc(N * 256 * 2);
  unsigned* cnt = (unsigned*)alloc(N * 4);
  unsigned* offs = (unsigned*)alloc(N * 4);
  unsigned* woff = (unsigned*)alloc(N * 4);
  unsigned* eid = (unsigned*)alloc((size_t)N_EDGES * 4);
  float* sbias = (float*)alloc((size_t)N_EDGES * 8 * 4);
  u8* AB = (u8*)alloc(N * 3072);  // e5m2, 201 MB; node-stage tensors alias it
  u8* wv = (u8*)d_out;            // E*256 fp8 == out_size bytes exactly
  float* x1 = (float*)AB;                        // 64 MB
  u16* X1cat = (u16*)(AB + (size_t)67108864);    // 64 MB
  float* x2 = (float*)(AB + (size_t)134217728);  // 64 MB
  u16* xn2 = (u16*)AB;                           // 32 MB (x1 dead)
  u16* Hf = (u16*)(AB + (size_t)33554432);       // 64 MB (X1cat dead)

  hipMemsetAsync(cnt, 0, N * 4, stream);
  hist_kernel<<<N_EDGES / 256, 256, 0, stream>>>(eidx + N_EDGES, cnt);
  scan_kernel<<<1, 1024, 0, stream>>>(cnt, offs, woff);
  scatter_ids<<<N_EDGES / 256, 256, 0, stream>>>(eidx + N_EDGES, woff, eid);
  sbias_kernel<<<N_EDGES * 8 / 256, 256, 0, stream>>>(eattr, sW1, sb1, sW2, sb2, sbias);
  prep_w1catT<<<3072, 256, 0, stream>>>(W1catT, qW1, kW1, vW1);
  prep_w2T<<<768, 256, 0, stream>>>(W2T, qW2, kW2, vW2);
  transpose_cast<<<256, 256, 0, stream>>>(rWT, rW, 512, 256);
  transpose_cast<<<512, 256, 0, stream>>>(fW1T, fW1, 256, 512);
  transpose_cast<<<256, 256, 0, stream>>>(fW2T, fW2, 512, 256);

  ln_kernel<<<N_NODES / 4, 256, 0, stream>>>(x, lng, lnb, xn);
  gemm_bt<<<dim3(N_NODES / 128, 3072 / 128), 256, 0, stream>>>(xn, W1catT, 256, EpiAB{AB});
  edge_kernel<<<N_EDGES / 32, 256, 0, stream>>>(eidx, eattr, AB, W2T, qb1, kb1, vb1, qb2, kb2,
                                                vb2, qW1, kW1, vW1, sbias, wv);
  node_gather<<<N_NODES / 4, 256, 0, stream>>>(offs, cnt, eid, wv, x, x1, X1cat);
  gemm_bt<<<dim3(N_NODES / 128, 2), 256, 0, stream>>>(X1cat, rWT, 512, EpiX2{x2, x1, rb});
  ln_kernel<<<N_NODES / 4, 256, 0, stream>>>(x2, lng, lnb, xn2);
  gemm_bt<<<dim3(N_NODES / 128, 4), 256, 0, stream>>>(xn2, fW1T, 256, EpiHf{Hf, fb1});
  gemm_bt<<<dim3(N_NODES / 128, 2), 256, 0, stream>>>(Hf, fW2T, 512, EpiOut{(float*)d_out, fb2, x2});
}